// Round 1
// baseline (147.383 us; speedup 1.0000x reference)
//
#include <hip/hip_runtime.h>

#define T_STEPS 20
#define NI 5
#define NH 100
#define NO 3

// One thread per batch element.
// Loop structure: h (hidden unit) OUTER, t (time) INNER fully unrolled.
// Each hidden unit's membrane depends only on its scalar drive c = cur1[b,h],
// so we evolve it standalone and scatter its spike train into cur2 accumulators
// acc[20][3] held in registers. Layer-2 dynamics run afterwards from acc.
//
// Rounding discipline: the reference (numpy fp32) computes
//   mem = (BETA*mem + cur) - reset*THRESH
// as separate mul/add/sub. We use __fmul_rn/__fadd_rn/__fsub_rn to forbid FMA
// contraction on the recurrences so threshold crossings match; dot products
// (order unknowable vs BLAS anyway) use FMA.
__global__ __launch_bounds__(256) void snn_kernel(
    const float* __restrict__ x,
    const float* __restrict__ W1,
    const float* __restrict__ b1,
    const float* __restrict__ W2,
    const float* __restrict__ b2,
    float* __restrict__ out, int B)
{
    int b = blockIdx.x * blockDim.x + threadIdx.x;
    if (b >= B) return;

    float xv[NI];
#pragma unroll
    for (int i = 0; i < NI; ++i) xv[i] = x[b * NI + i];

    float acc[T_STEPS][NO];
#pragma unroll
    for (int t = 0; t < T_STEPS; ++t)
#pragma unroll
        for (int o = 0; o < NO; ++o) acc[t][o] = 0.0f;

    for (int h = 0; h < NH; ++h) {
        // cur1[b,h] = x[b,:] . W1[h,:] + b1[h]   (wave-uniform W1/b1 -> s_load)
        float c = b1[h];
#pragma unroll
        for (int i = 0; i < NI; ++i) c = __builtin_fmaf(xv[i], W1[h * NI + i], c);

        float w0 = W2[0 * NH + h];
        float w1 = W2[1 * NH + h];
        float w2 = W2[2 * NH + h];

        float mem = 0.0f;
        bool sp = false;  // reset condition == previous spike condition (mem > 1)
#pragma unroll
        for (int t = 0; t < T_STEPS; ++t) {
            float tmp = __fmul_rn(0.95f, mem);
            tmp = __fadd_rn(tmp, c);
            mem = __fsub_rn(tmp, sp ? 1.0f : 0.0f);
            sp = mem > 1.0f;                 // == (mem - 1 > 0) exactly in fp32
            float spf = sp ? 1.0f : 0.0f;
            acc[t][0] = __builtin_fmaf(spf, w0, acc[t][0]);
            acc[t][1] = __builtin_fmaf(spf, w1, acc[t][1]);
            acc[t][2] = __builtin_fmaf(spf, w2, acc[t][2]);
        }
    }

    // Layer-2 LIF dynamics + spike count
    float m2[NO] = {0.0f, 0.0f, 0.0f};
    float cnt[NO] = {0.0f, 0.0f, 0.0f};
    bool r2[NO] = {false, false, false};
#pragma unroll
    for (int t = 0; t < T_STEPS; ++t) {
#pragma unroll
        for (int o = 0; o < NO; ++o) {
            float cur = __fadd_rn(acc[t][o], b2[o]);   // (sum) + b2, ref order
            float tmp = __fmul_rn(0.95f, m2[o]);
            tmp = __fadd_rn(tmp, cur);
            m2[o] = __fsub_rn(tmp, r2[o] ? 1.0f : 0.0f);
            r2[o] = m2[o] > 1.0f;
            cnt[o] = __fadd_rn(cnt[o], r2[o] ? 1.0f : 0.0f);
        }
    }
#pragma unroll
    for (int o = 0; o < NO; ++o) out[b * NO + o] = cnt[o];
}

extern "C" void kernel_launch(void* const* d_in, const int* in_sizes, int n_in,
                              void* d_out, int out_size, void* d_ws, size_t ws_size,
                              hipStream_t stream) {
    const float* x  = (const float*)d_in[0];
    const float* W1 = (const float*)d_in[1];
    const float* b1 = (const float*)d_in[2];
    const float* W2 = (const float*)d_in[3];
    const float* b2 = (const float*)d_in[4];
    float* out = (float*)d_out;

    int B = in_sizes[0] / NI;  // 262144
    int threads = 256;
    int blocks = (B + threads - 1) / threads;
    snn_kernel<<<blocks, threads, 0, stream>>>(x, W1, b1, W2, b2, out, B);
}